// Round 8
// baseline (469.828 us; speedup 1.0000x reference)
//
#include <hip/hip_runtime.h>
#include <hip/hip_bf16.h>

#define N_NODES_DIM0 128

typedef unsigned short u16;
typedef unsigned int u32;
typedef __attribute__((ext_vector_type(8))) short short8;
typedef __attribute__((ext_vector_type(4))) float f32x4;

__device__ __forceinline__ float bf2f(u16 h) { return __uint_as_float((u32)h << 16); }
__device__ __forceinline__ u16 f2bf(float f) {
    u32 u = __float_as_uint(f);
    u32 r = (u + 0x7FFFu + ((u >> 16) & 1u)) >> 16;  // round-to-nearest-even
    return (u16)r;
}

// async global->LDS, 16 B per lane; lds dest = wave-uniform base + lane*16
__device__ __forceinline__ void gl2lds16(const u16* g, u16* lds_base) {
    __builtin_amdgcn_global_load_lds(
        (const __attribute__((address_space(1))) u32*)g,
        (__attribute__((address_space(3))) u32*)lds_base, 16, 0, 0);
}

// ---------------- setup (merged kernels, R6-proven) ----------------

__global__ __launch_bounds__(256) void hist_wt_kernel(
    const int* __restrict__ dst, int* __restrict__ cnt, int e, int histB,
    const float* __restrict__ W0, const float* __restrict__ W1,
    const float* __restrict__ W2, const float* __restrict__ W3, u16* __restrict__ Wt) {
    __shared__ float tile[32][33];
    int bid = blockIdx.x;
    if (bid < histB) {
        int i = bid * 256 + threadIdx.x;
        if (i < e) atomicAdd(&cnt[dst[i]], 1);
        return;
    }
    bid -= histB;  // 0..783 W-transpose blocks
    const float* W; u16* out; int K, F, kb, nb;
    if (bid < 128)      { W = W0; out = Wt;          K = 128;  F = 1024; kb = bid & 3;  nb = bid >> 2; }
    else if (bid < 640) { int l = bid - 128; W = W1; out = Wt + 131072; K = 1024; F = 512; kb = l & 31; nb = l >> 5; }
    else if (bid < 768) { int l = bid - 640; W = W2; out = Wt + 655360; K = 512;  F = 256; kb = l & 15; nb = l >> 4; }
    else                { int l = bid - 768; W = W3; out = Wt + 786432; K = 256;  F = 64;  kb = l & 7;  nb = l >> 3; }
    int k0 = kb * 32, n0 = nb * 32;
    int tx = threadIdx.x & 31, ty = threadIdx.x >> 5;
#pragma unroll
    for (int i = 0; i < 4; ++i) {
        int k = ty + i * 8;
        tile[k][tx] = W[(size_t)(k0 + k) * F + n0 + tx];  // coalesced 128B rows
    }
    __syncthreads();
#pragma unroll
    for (int i = 0; i < 4; ++i) {
        int n = ty + i * 8;
        out[(size_t)(n0 + n) * K + k0 + tx] = f2bf(tile[tx][n]);  // coalesced bf16 rows
    }
}

__global__ void alloc_kernel(const int* __restrict__ cnt, int* __restrict__ row_start,
                             float* __restrict__ dinv, int* __restrict__ cursor, int n) {
    int i = blockIdx.x * blockDim.x + threadIdx.x;
    int lane = threadIdx.x & 63;
    int v = (i < n) ? cnt[i] : 0;
    int s = v;  // inclusive wave prefix
#pragma unroll
    for (int off = 1; off < 64; off <<= 1) {
        int x = __shfl_up(s, off, 64);
        if (lane >= off) s += x;
    }
    int total = __shfl(s, 63, 64);
    int base = 0;
    if (lane == 0) base = atomicAdd(cursor, total);
    base = __shfl(base, 0, 64);
    if (i < n) {
        row_start[i] = base + s - v;  // exclusive within wave
        dinv[i] = rsqrtf((float)v + 1.0f);
    }
}

__global__ __launch_bounds__(256) void fill_y_kernel(
    const int* __restrict__ src, const int* __restrict__ dst,
    int* __restrict__ row_start, int* __restrict__ csr_src, int e, int fillB,
    const float* __restrict__ x, const float* __restrict__ dinv,
    u16* __restrict__ Y, int N) {
    int bid = blockIdx.x;
    if (bid < fillB) {
        int i = bid * 256 + threadIdx.x;
        if (i < e) {
            int d = dst[i];
            int pos = atomicAdd(&row_start[d], 1);
            csr_src[pos] = src[i];
        }
        return;
    }
    int gid = (bid - fillB) * 256 + threadIdx.x;
    int node = gid >> 5;
    int c4 = (gid & 31) * 4;
    if (node >= N) return;
    float dv = dinv[node];
    float4 v = *reinterpret_cast<const float4*>(x + (size_t)node * 128 + c4);
    ushort4 r;
    r.x = f2bf(dv * v.x); r.y = f2bf(dv * v.y);
    r.z = f2bf(dv * v.z); r.w = f2bf(dv * v.w);
    *reinterpret_cast<ushort4*>(Y + (size_t)node * 128 + c4) = r;
}

// ---------------- helpers: bf16x8 accumulate ----------------
__device__ __forceinline__ void add8v(float* acc, short8 v) {
#pragma unroll
    for (int w = 0; w < 8; ++w) acc[w] += bf2f((u16)v[w]);
}
__device__ __forceinline__ void add16p(float* acc, const u16* p) {
    short8 a = *reinterpret_cast<const short8*>(p);
    short8 b = *reinterpret_cast<const short8*>(p + 8);
    add8v(acc, a); add8v(acc + 8, b);
}

// 16-channel CSR gather-accumulate (pinned at ~3.9-4.0 TB/s service rate; R0/R1/R4)
__device__ __forceinline__ void gather_sum16(float* acc, const u16* __restrict__ base,
                                             const int* __restrict__ csr_src,
                                             int beg, int end, int stride, int ch) {
    int e = beg;
    int nfull = (end - beg) >> 3;
    if (nfull > 0) {
        int i0 = csr_src[e],     i1 = csr_src[e + 1], i2 = csr_src[e + 2], i3 = csr_src[e + 3];
        int i4 = csr_src[e + 4], i5 = csr_src[e + 5], i6 = csr_src[e + 6], i7 = csr_src[e + 7];
        for (int b = 0; b < nfull; ++b) {
            const u16* p0 = base + (size_t)i0 * stride + ch;
            const u16* p1 = base + (size_t)i1 * stride + ch;
            const u16* p2 = base + (size_t)i2 * stride + ch;
            const u16* p3 = base + (size_t)i3 * stride + ch;
            const u16* p4 = base + (size_t)i4 * stride + ch;
            const u16* p5 = base + (size_t)i5 * stride + ch;
            const u16* p6 = base + (size_t)i6 * stride + ch;
            const u16* p7 = base + (size_t)i7 * stride + ch;
            short8 a0 = *reinterpret_cast<const short8*>(p0), b0 = *reinterpret_cast<const short8*>(p0 + 8);
            short8 a1 = *reinterpret_cast<const short8*>(p1), b1 = *reinterpret_cast<const short8*>(p1 + 8);
            short8 a2 = *reinterpret_cast<const short8*>(p2), b2 = *reinterpret_cast<const short8*>(p2 + 8);
            short8 a3 = *reinterpret_cast<const short8*>(p3), b3 = *reinterpret_cast<const short8*>(p3 + 8);
            short8 a4 = *reinterpret_cast<const short8*>(p4), b4 = *reinterpret_cast<const short8*>(p4 + 8);
            short8 a5 = *reinterpret_cast<const short8*>(p5), b5 = *reinterpret_cast<const short8*>(p5 + 8);
            short8 a6 = *reinterpret_cast<const short8*>(p6), b6 = *reinterpret_cast<const short8*>(p6 + 8);
            short8 a7 = *reinterpret_cast<const short8*>(p7), b7 = *reinterpret_cast<const short8*>(p7 + 8);
            e += 8;
            int ep = (e + 8 <= end) ? e : beg;
            i0 = csr_src[ep];     i1 = csr_src[ep + 1]; i2 = csr_src[ep + 2]; i3 = csr_src[ep + 3];
            i4 = csr_src[ep + 4]; i5 = csr_src[ep + 5]; i6 = csr_src[ep + 6]; i7 = csr_src[ep + 7];
            __builtin_amdgcn_sched_barrier(0);
            add8v(acc, a0); add8v(acc + 8, b0);
            add8v(acc, a1); add8v(acc + 8, b1);
            add8v(acc, a2); add8v(acc + 8, b2);
            add8v(acc, a3); add8v(acc + 8, b3);
            add8v(acc, a4); add8v(acc + 8, b4);
            add8v(acc, a5); add8v(acc + 8, b5);
            add8v(acc, a6); add8v(acc + 8, b6);
            add8v(acc, a7); add8v(acc + 8, b7);
        }
    }
    for (; e + 4 <= end; e += 4) {
        const u16* p0 = base + (size_t)csr_src[e]     * stride + ch;
        const u16* p1 = base + (size_t)csr_src[e + 1] * stride + ch;
        const u16* p2 = base + (size_t)csr_src[e + 2] * stride + ch;
        const u16* p3 = base + (size_t)csr_src[e + 3] * stride + ch;
        short8 a0 = *reinterpret_cast<const short8*>(p0), b0 = *reinterpret_cast<const short8*>(p0 + 8);
        short8 a1 = *reinterpret_cast<const short8*>(p1), b1 = *reinterpret_cast<const short8*>(p1 + 8);
        short8 a2 = *reinterpret_cast<const short8*>(p2), b2 = *reinterpret_cast<const short8*>(p2 + 8);
        short8 a3 = *reinterpret_cast<const short8*>(p3), b3 = *reinterpret_cast<const short8*>(p3 + 8);
        __builtin_amdgcn_sched_barrier(0);
        add8v(acc, a0); add8v(acc + 8, b0);
        add8v(acc, a1); add8v(acc + 8, b1);
        add8v(acc, a2); add8v(acc + 8, b2);
        add8v(acc, a3); add8v(acc + 8, b3);
    }
    for (; e < end; ++e) {
        const u16* p = base + (size_t)csr_src[e] * stride + ch;
        short8 a = *reinterpret_cast<const short8*>(p), b = *reinterpret_cast<const short8*>(p + 8);
        add8v(acc, a); add8v(acc + 8, b);
    }
}

// ---------------- aggregation device body (node-range partitioned) ----------------
template <int TPB, int MODE>
__device__ __forceinline__ void agg_dev(
        int bid, int t, const int* __restrict__ row_end, const int* __restrict__ cnt,
        const int* __restrict__ csr_src, const u16* Gin, const float* __restrict__ dinv,
        const float* __restrict__ bias, u16* XO, int nodeBeg, int nodeEnd, int F, int lgG) {
    int gid = bid * TPB + t;
    int node = nodeBeg + (gid >> lgG);
    int ch = (gid & ((1 << lgG) - 1)) * 16;
    if (node >= nodeEnd) return;
    float acc[16] = {};
    add16p(acc, Gin + (size_t)node * F + ch);  // self-loop
    int end = row_end[node], beg = end - cnt[node];
    gather_sum16(acc, Gin, csr_src, beg, end, F, ch);
    float dv = dinv[node];
    short8 r0, r1;
#pragma unroll
    for (int w = 0; w < 8; ++w) {
        if (MODE == 0) {
            r0[w] = (short)f2bf(dv * acc[w]);
            r1[w] = (short)f2bf(dv * acc[8 + w]);
        } else {
            r0[w] = (short)f2bf(fmaxf(fmaf(dv, acc[w], bias[ch + w]), 0.f));
            r1[w] = (short)f2bf(fmaxf(fmaf(dv, acc[8 + w], bias[ch + 8 + w]), 0.f));
        }
    }
    *reinterpret_cast<short8*>(XO + (size_t)node * F + ch) = r0;
    *reinterpret_cast<short8*>(XO + (size_t)node * F + ch + 8) = r1;
}

template <int TPB, int MODE>
__global__ __launch_bounds__(TPB, 4) void agg_kernel(
        const int* __restrict__ row_end, const int* __restrict__ cnt,
        const int* __restrict__ csr_src, const u16* Gin, const float* __restrict__ dinv,
        const float* __restrict__ bias, u16* XO, int nodeBeg, int nodeEnd, int F, int lgG) {
    agg_dev<TPB, MODE>(blockIdx.x, threadIdx.x, row_end, cnt, csr_src, Gin, dinv, bias, XO,
                       nodeBeg, nodeEnd, F, lgG);
}

// ---------------- MFMA bf16 GEMM device body (row-range partitioned) ----------------
template <int BN, int TPB, int EPI>
__device__ __forceinline__ void gemm_dev(
    u16* As, u16* Bs, int bid, int t,
    const u16* X, const u16* __restrict__ Wt,
    const float* __restrict__ dinv, const float* __restrict__ bias,
    u16* Out, int rowBeg, int rowEnd, int N, int K, int F, int lgnx) {
    constexpr int BM = 128, BK = 64;
    constexpr int RA = (BM * 8) / TPB;
    constexpr int RB = (BN * 8) / TPB;
    constexpr int WAVES = TPB / 64;
    constexpr int WAVES_N = (BN >= 64) ? (BN / 64) : 1;
    constexpr int WAVES_M = WAVES / WAVES_N;
    constexpr int WM = BM / WAVES_M;
    constexpr int WN = BN / WAVES_N;
    constexpr int NI = WM / 16;
    constexpr int NJ = WN / 16;

    const int wave = t >> 6;
    const int lane = t & 63;
    const int m16 = lane & 15;
    const int quad = lane >> 4;

    // XCD-aware decode
    const int wi = bid & ((8 << lgnx) - 1);
    const int g  = bid >> (3 + lgnx);
    const int rb = g * 8 + (wi & 7);
    const int cb = wi >> 3;
    const int row0 = rowBeg + rb * BM;
    const int col0 = cb * BN;
    if (row0 >= rowEnd) return;

    const int wm = (wave / WAVES_N) * WM;
    const int wn = (wave % WAVES_N) * WN;

    const u16* aSrc[RA];
    u16* aDst[RA];
#pragma unroll
    for (int rr = 0; rr < RA; ++rr) {
        int c = rr * TPB + t;
        int r = c >> 3;
        int q = (c ^ r) & 7;  // XOR swizzle
        int grow = row0 + r;
        if (grow >= N) grow = 0;  // clamped rows feed only epilogue-guarded outputs
        aSrc[rr] = X + (size_t)grow * K + q * 8;
        aDst[rr] = &As[(size_t)(rr * TPB + wave * 64) * 8];
    }
    const u16* bSrc[RB];
    u16* bDst[RB];
#pragma unroll
    for (int rr = 0; rr < RB; ++rr) {
        int c = rr * TPB + t;
        int r = c >> 3;
        int q = (c ^ r) & 7;
        bSrc[rr] = Wt + (size_t)(col0 + r) * K + q * 8;
        bDst[rr] = &Bs[(size_t)(rr * TPB + wave * 64) * 8];
    }

    u32 aOff[NI][2], bOff[NJ][2];
#pragma unroll
    for (int i = 0; i < NI; ++i)
#pragma unroll
        for (int h = 0; h < 2; ++h) {
            int row = wm + i * 16 + m16;
            int qg = h * 4 + quad;
            aOff[i][h] = (u32)(((row << 3) | ((qg ^ row) & 7)) * 16);
        }
#pragma unroll
    for (int j = 0; j < NJ; ++j)
#pragma unroll
        for (int h = 0; h < 2; ++h) {
            int row = wn + j * 16 + m16;
            int qg = h * 4 + quad;
            bOff[j][h] = (u32)(((row << 3) | ((qg ^ row) & 7)) * 16);
        }
    const char* AsB = reinterpret_cast<const char*>(As);
    const char* BsB = reinterpret_cast<const char*>(Bs);

    f32x4 acc[NI][NJ] = {};

    for (int k0 = 0; k0 < K; k0 += BK) {
#pragma unroll
        for (int rr = 0; rr < RA; ++rr) {
            gl2lds16(aSrc[rr], aDst[rr]);
            aSrc[rr] += BK;
        }
#pragma unroll
        for (int rr = 0; rr < RB; ++rr) {
            gl2lds16(bSrc[rr], bDst[rr]);
            bSrc[rr] += BK;
        }
        __syncthreads();  // drains vmcnt -> LDS valid

#pragma unroll
        for (int h = 0; h < 2; ++h) {
            short8 af[NI], bf[NJ];
#pragma unroll
            for (int i = 0; i < NI; ++i)
                af[i] = *reinterpret_cast<const short8*>(AsB + aOff[i][h]);
#pragma unroll
            for (int j = 0; j < NJ; ++j)
                bf[j] = *reinterpret_cast<const short8*>(BsB + bOff[j][h]);
#pragma unroll
            for (int i = 0; i < NI; ++i)
#pragma unroll
                for (int j = 0; j < NJ; ++j)
                    acc[i][j] = __builtin_amdgcn_mfma_f32_16x16x32_bf16(af[i], bf[j], acc[i][j], 0, 0, 0);
        }
        __syncthreads();
    }

    // epilogue: C/D layout col=lane&15, row=quad*4+reg  [measured m89/m91]
#pragma unroll
    for (int i = 0; i < NI; ++i) {
#pragma unroll
        for (int r = 0; r < 4; ++r) {
            int grow = row0 + wm + i * 16 + quad * 4 + r;
            if (grow >= N) continue;
            float dv = (EPI == 0) ? dinv[grow] : 0.f;
#pragma unroll
            for (int j = 0; j < NJ; ++j) {
                int gcol = col0 + wn + j * 16 + m16;
                float v = acc[i][j][r];
                if (EPI == 0) v = dv * v;
                else          v = fmaxf(v + bias[gcol], 0.f);
                Out[(size_t)grow * F + gcol] = f2bf(v);
            }
        }
    }
}

template <int BN, int TPB, int EPI>
__global__ __launch_bounds__(TPB) void gemm_mfma_kernel(
    const u16* X, const u16* __restrict__ Wt,
    const float* __restrict__ dinv, const float* __restrict__ bias,
    u16* Out, int rowBeg, int rowEnd, int N, int K, int F, int lgnx) {
    __shared__ u16 As[128 * 64];
    __shared__ u16 Bs[BN * 64];
    gemm_dev<BN, TPB, EPI>(As, Bs, blockIdx.x, threadIdx.x, X, Wt, dinv, bias, Out,
                           rowBeg, rowEnd, N, K, F, lgnx);
}

// ---------------- interleaved role split (R8 fix of R5's ordering failure) ----------------
// In-order block dispatch means bid<nG-first layouts run the two roles SEQUENTIALLY.
// Interleave: every k-th block takes the rarer role -> both populations co-occupy CUs
// from t=0. Exact bijection: small role at bid = q*k (q < nSmall); big role otherwise,
// bigIdx = bid - (#small blocks at or before bid).
__device__ __forceinline__ bool pick_role(int bid, int nSmall, int k, int& sIdx, int& bIdx) {
    int q = bid / k;
    int r = bid - q * k;
    if (r == 0 && q < nSmall) { sIdx = q; return true; }
    bIdx = bid - ((q < nSmall) ? (q + (r ? 1 : 0)) : nSmall);
    return false;
}

// pair 1: agg_pre(h1) || gemm1(h0)
__global__ __launch_bounds__(512) void fused_aggpre_gemm1_kernel(
        const int* __restrict__ row_end, const int* __restrict__ cnt,
        const int* __restrict__ csr_src, const u16* Y, const float* __restrict__ dinv,
        u16* Z, const u16* __restrict__ Wt0, const float* __restrict__ b0, u16* XA,
        int nSmall, int k, int aggSmall, int M0, int N) {
    __shared__ u16 As[128 * 64];
    __shared__ u16 Bs[256 * 64];
    int sIdx, bIdx;
    bool isSmall = pick_role(blockIdx.x, nSmall, k, sIdx, bIdx);
    int idx = isSmall ? sIdx : bIdx;
    if (isSmall == (aggSmall != 0))
        agg_dev<512, 0>(idx, threadIdx.x, row_end, cnt, csr_src, Y, dinv, nullptr, Z,
                        M0, N, 128, 3);
    else
        gemm_dev<256, 512, 1>(As, Bs, idx, threadIdx.x, Z, Wt0, dinv, b0, XA,
                              0, M0, N, 128, 1024, 2);
}

// pair 2: agg2(h1) || gemm3(h0) -> Gc256
__global__ __launch_bounds__(512) void fused_agg2_gemm3_kernel(
        const int* __restrict__ row_end, const int* __restrict__ cnt,
        const int* __restrict__ csr_src, const u16* Gc512, const float* __restrict__ dinv,
        const float* __restrict__ b1, u16* XB, const u16* __restrict__ Wt2, u16* Gc256,
        int nSmall, int k, int aggSmall, int M0, int N) {
    __shared__ u16 As[128 * 64];
    __shared__ u16 Bs[256 * 64];
    int sIdx, bIdx;
    bool isSmall = pick_role(blockIdx.x, nSmall, k, sIdx, bIdx);
    int idx = isSmall ? sIdx : bIdx;
    if (isSmall == (aggSmall != 0))
        agg_dev<512, 1>(idx, threadIdx.x, row_end, cnt, csr_src, Gc512, dinv, b1, XB,
                        M0, N, 512, 5);
    else
        gemm_dev<256, 512, 0>(As, Bs, idx, threadIdx.x, XB, Wt2, dinv, b1, Gc256,
                              0, M0, N, 512, 256, 0);
}

// pair 3: agg3(h1) || gemm4(h0) -> Gc64
__global__ __launch_bounds__(512) void fused_agg3_gemm4_kernel(
        const int* __restrict__ row_end, const int* __restrict__ cnt,
        const int* __restrict__ csr_src, const u16* Gc256, const float* __restrict__ dinv,
        const float* __restrict__ b2, u16* XAlow, const u16* __restrict__ Wt3,
        const float* __restrict__ b3, u16* Gc64,
        int nSmall, int k, int aggSmall, int M0, int N) {
    __shared__ u16 As[128 * 64];
    __shared__ u16 Bs[64 * 64];
    int sIdx, bIdx;
    bool isSmall = pick_role(blockIdx.x, nSmall, k, sIdx, bIdx);
    int idx = isSmall ? sIdx : bIdx;
    if (isSmall == (aggSmall != 0))
        agg_dev<512, 1>(idx, threadIdx.x, row_end, cnt, csr_src, Gc256, dinv, b2, XAlow,
                        M0, N, 256, 4);
    else
        gemm_dev<64, 512, 0>(As, Bs, idx, threadIdx.x, XAlow, Wt3, dinv, b3, Gc64,
                             0, M0, N, 256, 64, 0);
}

// ---------------- fused layer-4 aggregation + layer-5 dot ----------------
__global__ __launch_bounds__(256, 4) void agg_post_l5_kernel(
        const int* __restrict__ row_end, const int* __restrict__ cnt,
        const int* __restrict__ csr_src,
        const u16* __restrict__ Gc, const float* __restrict__ dinv,
        const float* __restrict__ b4, const float* __restrict__ W5,
        float* __restrict__ g5, int N) {
    int gid = blockIdx.x * blockDim.x + threadIdx.x;
    int node = gid >> 2;          // 4 threads/node
    int ch = (gid & 3) * 16;      // 16 cols each
    if (node >= N) return;
    float acc[16] = {};
    add16p(acc, Gc + (size_t)node * 64 + ch);  // self-loop
    int end = row_end[node], beg = end - cnt[node];
    gather_sum16(acc, Gc, csr_src, beg, end, 64, ch);
    float dv = dinv[node];
    float dot = 0.f;
#pragma unroll
    for (int w = 0; w < 16; ++w) {
        float v = fmaxf(fmaf(dv, acc[w], b4[ch + w]), 0.f);  // fp32 activation
        dot = fmaf(v, W5[ch + w], dot);
    }
#pragma unroll
    for (int off = 2; off > 0; off >>= 1) dot += __shfl_down(dot, off, 4);
    if ((gid & 3) == 0) g5[node] = dv * dot;
}

__global__ void agg5_kernel(const int* __restrict__ row_end, const int* __restrict__ cnt,
                            const int* __restrict__ csr_src,
                            const float* __restrict__ g5, const float* __restrict__ dinv,
                            const float* __restrict__ b5, float* __restrict__ out, int N) {
    int i = blockIdx.x * blockDim.x + threadIdx.x;
    if (i >= N) return;
    float acc = g5[i];
    int end = row_end[i], e = end - cnt[i];
    for (; e + 4 <= end; e += 4) {
        float a = g5[csr_src[e]];
        float b = g5[csr_src[e + 1]];
        float c = g5[csr_src[e + 2]];
        float d = g5[csr_src[e + 3]];
        acc += (a + b) + (c + d);
    }
    for (; e < end; ++e) acc += g5[csr_src[e]];
    out[i] = fmaxf(fmaf(dinv[i], acc, b5[0]), 0.f);
}

// ---------------- launch ----------------

static inline size_t align_up(size_t x) { return (x + 255) & ~(size_t)255; }
static inline int round_up8(int x) { return (x + 7) & ~7; }

extern "C" void kernel_launch(void* const* d_in, const int* in_sizes, int n_in,
                              void* d_out, int out_size, void* d_ws, size_t ws_size,
                              hipStream_t stream) {
    const float* x  = (const float*)d_in[0];
    const int*   ei = (const int*)d_in[1];
    const int E = in_sizes[1] / 2;
    const int N = in_sizes[0] / N_NODES_DIM0;
    const int* src = ei;
    const int* dst = ei + E;

    const float* W[5] = {(const float*)d_in[2], (const float*)d_in[4], (const float*)d_in[6],
                         (const float*)d_in[8], (const float*)d_in[10]};
    const float* B[5] = {(const float*)d_in[3], (const float*)d_in[5], (const float*)d_in[7],
                         (const float*)d_in[9], (const float*)d_in[11]};

    const int Ks[4] = {128, 1024, 512, 256};
    const int Fs[4] = {1024, 512, 256, 64};

    // workspace carve — peak ~209 MB
    char* w = (char*)d_ws;
    size_t off = 0;
    float* dinv    = (float*)(w + off); off += align_up((size_t)N * 4);
    float* g5      = (float*)(w + off); off += align_up((size_t)N * 4);
    int*   cnt     = (int*)(w + off);   off += align_up((size_t)(N + 1) * 4);  // cnt[N] = cursor
    int*   rstart  = (int*)(w + off);   off += align_up((size_t)N * 4);        // bump ptr -> row end
    int*   csr_src = (int*)(w + off);   off += align_up((size_t)E * 4);        // 1.6 MB
    u16* WtBase = (u16*)(w + off);
    u16* Wt[4];
    {
        size_t cum = 0;
        for (int l = 0; l < 4; ++l) {
            Wt[l] = WtBase + cum;
            cum += (size_t)Ks[l] * Fs[l];
        }
        off += align_up(cum * 2);
    }
    char* REG = w + off;               off += align_up((size_t)N * 512 * 2);    // 51.2 MB
    u16* Y  = (u16*)REG;
    u16* Z  = (u16*)(REG + align_up((size_t)N * 128 * 2));
    u16* Gc = (u16*)REG;               // 512-wide (G2 out) / 64-wide (G4 out)
    u16* XA = (u16*)(w + off);         off += align_up((size_t)N * 1024 * 2);   // 102.4 MB
    u16* XB = (u16*)(w + off);         off += align_up((size_t)N * 512 * 2);    // 51.2 MB
    u16* Gc256 = XA + (size_t)N * 512; // upper half of XA arena (free after gemm2)
    (void)ws_size;

    // ---- setup (4 nodes) ----
    hipMemsetAsync(cnt, 0, (size_t)(N + 1) * 4, stream);
    {
        int histB = (E + 255) / 256;
        hist_wt_kernel<<<histB + 784, 256, 0, stream>>>(dst, cnt, E, histB,
                                                        W[0], W[1], W[2], W[3], WtBase);
    }
    alloc_kernel<<<(N + 255) / 256, 256, 0, stream>>>(cnt, rstart, dinv, &cnt[N], N);
    {
        int fillB = (E + 255) / 256;
        int yB = (N * 32 + 255) / 256;
        fill_y_kernel<<<fillB + yB, 256, 0, stream>>>(src, dst, rstart, csr_src, E, fillB,
                                                      x, dinv, Y, N);
    }

    const int ny  = (N + 127) / 128;
    const int nyh = (ny + 1) / 2;
    const int M0  = nyh * 128;               // row-half boundary (BM-aligned)
    const int ny8  = round_up8(ny);
    const int ny8h = round_up8(nyh);
    const int ny8r = round_up8(ny - nyh);
    const int h1nodes = (N > M0) ? (N - M0) : 0;

    auto split = [](int nA, int nG, int& nSmall, int& k, int& aggSmall) {
        if (nA <= nG) { nSmall = nA; aggSmall = 1; } else { nSmall = nG; aggSmall = 0; }
        int T = nA + nG;
        k = (nSmall > 0) ? (T / nSmall) : 1;
        if (k < 1) k = 1;
    };

    // ---- layer 1: agg_pre(h0); [agg_pre(h1) || gemm1(h0)] interleaved; gemm1(h1) ----
    agg_kernel<256, 0><<<(M0 * 8 + 255) / 256, 256, 0, stream>>>(
        rstart, cnt, csr_src, Y, dinv, nullptr, Z, 0, M0 < N ? M0 : N, 128, 3);
    {
        int nG = ny8h * 4;                    // lgnx=2 decode needs multiple of 32 -> ok
        int nA = (h1nodes * 8 + 511) / 512;
        int nS, k, aS; split(nA, nG, nS, k, aS);
        fused_aggpre_gemm1_kernel<<<nA + nG, 512, 0, stream>>>(
            rstart, cnt, csr_src, Y, dinv, Z, Wt[0], B[0], XA, nS, k, aS, M0, N);
    }
    if (ny > nyh)
        gemm_mfma_kernel<256, 512, 1><<<ny8r * 4, 512, 0, stream>>>(
            Z, Wt[0], dinv, B[0], XA, M0, N, N, 128, 1024, 2);

    // ---- layer 2 GEMM (full): Gc512 = dinv * (XA @ W2) ----
    gemm_mfma_kernel<256, 512, 0><<<ny8 * 2, 512, 0, stream>>>(
        XA, Wt[1], dinv, B[1], Gc, 0, N, N, 1024, 512, 1);

    // ---- agg2(h0); [agg2(h1) || gemm3(h0) -> Gc256] interleaved; gemm3(h1) ----
    agg_kernel<256, 1><<<(M0 * 32 + 255) / 256, 256, 0, stream>>>(
        rstart, cnt, csr_src, Gc, dinv, B[1], XB, 0, M0 < N ? M0 : N, 512, 5);
    {
        int nG = ny8h;
        int nA = (h1nodes * 32 + 511) / 512;
        int nS, k, aS; split(nA, nG, nS, k, aS);
        fused_agg2_gemm3_kernel<<<nA + nG, 512, 0, stream>>>(
            rstart, cnt, csr_src, Gc, dinv, B[1], XB, Wt[2], Gc256, nS, k, aS, M0, N);
    }
    if (ny > nyh)
        gemm_mfma_kernel<256, 512, 0><<<ny8r, 512, 0, stream>>>(
            XB, Wt[2], dinv, B[1], Gc256, M0, N, N, 512, 256, 0);

    // ---- agg3(h0) -> XAlow; [agg3(h1) || gemm4(h0) -> Gc64] interleaved; gemm4(h1) ----
    agg_kernel<256, 1><<<(M0 * 16 + 255) / 256, 256, 0, stream>>>(
        rstart, cnt, csr_src, Gc256, dinv, B[2], XA, 0, M0 < N ? M0 : N, 256, 4);
    {
        int nG = ny8h;
        int nA = (h1nodes * 16 + 511) / 512;
        int nS, k, aS; split(nA, nG, nS, k, aS);
        fused_agg3_gemm4_kernel<<<nA + nG, 512, 0, stream>>>(
            rstart, cnt, csr_src, Gc256, dinv, B[2], XA, Wt[3], B[3], Gc, nS, k, aS, M0, N);
    }
    if (ny > nyh)
        gemm_mfma_kernel<64, 512, 0><<<ny8r, 512, 0, stream>>>(
            XA, Wt[3], dinv, B[3], Gc, M0, N, N, 256, 64, 0);

    // ---- fused layer-4 agg + layer-5 dot (full) ----
    agg_post_l5_kernel<<<(unsigned)(((long long)N * 4 + 255) / 256), 256, 0, stream>>>(
        rstart, cnt, csr_src, Gc, dinv, B[3], W[4], g5, N);

    // ---- layer 5 aggregation: out = relu(dinv*(g5[d]+sum g5[src]) + b5) ----
    agg5_kernel<<<(N + 255) / 256, 256, 0, stream>>>(rstart, cnt, csr_src, g5, dinv, B[4],
                                                     (float*)d_out, N);
}

// Round 10
// 413.588 us; speedup vs baseline: 1.1360x; 1.1360x over previous
//
#include <hip/hip_runtime.h>
#include <hip/hip_bf16.h>

#define N_NODES_DIM0 128

typedef unsigned short u16;
typedef unsigned int u32;
typedef __attribute__((ext_vector_type(8))) short short8;
typedef __attribute__((ext_vector_type(4))) float f32x4;

__device__ __forceinline__ float bf2f(u16 h) { return __uint_as_float((u32)h << 16); }
__device__ __forceinline__ u16 f2bf(float f) {
    u32 u = __float_as_uint(f);
    u32 r = (u + 0x7FFFu + ((u >> 16) & 1u)) >> 16;  // round-to-nearest-even
    return (u16)r;
}

// async global->LDS, 16 B per lane; lds dest = wave-uniform base + lane*16
__device__ __forceinline__ void gl2lds16(const u16* g, u16* lds_base) {
    __builtin_amdgcn_global_load_lds(
        (const __attribute__((address_space(1))) u32*)g,
        (__attribute__((address_space(3))) u32*)lds_base, 16, 0, 0);
}

// ---------------- CSR build (scan-free: wave-scan + atomic bump allocator) ----------------

__global__ void hist_kernel(const int* __restrict__ dst, int* __restrict__ cnt, int e) {
    int i = blockIdx.x * blockDim.x + threadIdx.x;
    if (i < e) atomicAdd(&cnt[dst[i]], 1);
}

// row_start[i] = segment base (segments in arbitrary order); dinv[i] = rsqrt(deg+1).
__global__ void alloc_kernel(const int* __restrict__ cnt, int* __restrict__ row_start,
                             float* __restrict__ dinv, int* __restrict__ cursor, int n) {
    int i = blockIdx.x * blockDim.x + threadIdx.x;
    int lane = threadIdx.x & 63;
    int v = (i < n) ? cnt[i] : 0;
    int s = v;  // inclusive wave prefix
#pragma unroll
    for (int off = 1; off < 64; off <<= 1) {
        int x = __shfl_up(s, off, 64);
        if (lane >= off) s += x;
    }
    int total = __shfl(s, 63, 64);
    int base = 0;
    if (lane == 0) base = atomicAdd(cursor, total);
    base = __shfl(base, 0, 64);
    if (i < n) {
        row_start[i] = base + s - v;  // exclusive within wave
        dinv[i] = rsqrtf((float)v + 1.0f);
    }
}

// bump-fill: after completion row_start[d] == segment end (beg = end - cnt[d])
__global__ void fill_kernel(const int* __restrict__ src, const int* __restrict__ dst,
                            int* __restrict__ row_start, int* __restrict__ csr_src, int e) {
    int i = blockIdx.x * blockDim.x + threadIdx.x;
    if (i < e) {
        int d = dst[i];
        int pos = atomicAdd(&row_start[d], 1);
        csr_src[pos] = src[i];
    }
}

// ---------------- merged: LDS-tiled weight transpose-cast + input scale-cast ----------------
__global__ __launch_bounds__(256) void prep_kernel(
    const float* __restrict__ W0, const float* __restrict__ W1,
    const float* __restrict__ W2, const float* __restrict__ W3, u16* __restrict__ Wt,
    const float* __restrict__ x, const float* __restrict__ dinv,
    u16* __restrict__ Y, int N) {
    int bid = blockIdx.x;
    if (bid < 784) {
        __shared__ float tile[32][33];
        const float* W; u16* out; int K, F, kb, nb;
        if (bid < 128)      { W = W0; out = Wt;          K = 128;  F = 1024; kb = bid & 3;  nb = bid >> 2; }
        else if (bid < 640) { int l = bid - 128; W = W1; out = Wt + 131072; K = 1024; F = 512; kb = l & 31; nb = l >> 5; }
        else if (bid < 768) { int l = bid - 640; W = W2; out = Wt + 655360; K = 512;  F = 256; kb = l & 15; nb = l >> 4; }
        else                { int l = bid - 768; W = W3; out = Wt + 786432; K = 256;  F = 64;  kb = l & 7;  nb = l >> 3; }
        int k0 = kb * 32, n0 = nb * 32;
        int tx = threadIdx.x & 31, ty = threadIdx.x >> 5;
#pragma unroll
        for (int i = 0; i < 4; ++i) {
            int k = ty + i * 8;
            tile[k][tx] = W[(size_t)(k0 + k) * F + n0 + tx];  // coalesced 128B rows
        }
        __syncthreads();
#pragma unroll
        for (int i = 0; i < 4; ++i) {
            int n = ty + i * 8;
            out[(size_t)(n0 + n) * K + k0 + tx] = f2bf(tile[tx][n]);  // coalesced bf16 rows
        }
    } else {
        int gid = (bid - 784) * 256 + threadIdx.x;
        int node = gid >> 5;
        int c4 = (gid & 31) * 4;
        if (node >= N) return;
        float dv = dinv[node];
        float4 v = *reinterpret_cast<const float4*>(x + (size_t)node * 128 + c4);
        ushort4 r;
        r.x = f2bf(dv * v.x); r.y = f2bf(dv * v.y);
        r.z = f2bf(dv * v.z); r.w = f2bf(dv * v.w);
        *reinterpret_cast<ushort4*>(Y + (size_t)node * 128 + c4) = r;
    }
}

// ---------------- helpers: bf16x8 accumulate ----------------
__device__ __forceinline__ void add8v(float* acc, short8 v) {
#pragma unroll
    for (int w = 0; w < 8; ++w) acc[w] += bf2f((u16)v[w]);
}
// self-row: 16 contiguous channels starting at p
__device__ __forceinline__ void add16p(float* acc, const u16* p) {
    short8 a = *reinterpret_cast<const short8*>(p);
    short8 b = *reinterpret_cast<const short8*>(p + 8);
    add8v(acc, a); add8v(acc + 8, b);
}

// 16-channel CSR gather-accumulate. Latency-bound random gathers: each lane owns
// 16 contiguous channels -> 2x16B loads per gathered row sharing one address calc.
// R1: the compiler serialized R0's 16-load batch (VGPR stayed 48 -> ~5 loads in
// flight). Force the schedule: sched_barrier(0) pins {16 data loads + next-batch
// index prefetch} ABOVE the add cluster, so all 16 short8 results are live
// simultaneously (true 16-deep MLP). Index prefetch above the barrier keeps the
// next batch's csr_src latency hidden under the current adds.
__device__ __forceinline__ void gather_sum16(float* acc, const u16* __restrict__ base,
                                             const int* __restrict__ csr_src,
                                             int beg, int end, int stride, int ch) {
    int e = beg;
    int nfull = (end - beg) >> 3;
    if (nfull > 0) {
        int i0 = csr_src[e],     i1 = csr_src[e + 1], i2 = csr_src[e + 2], i3 = csr_src[e + 3];
        int i4 = csr_src[e + 4], i5 = csr_src[e + 5], i6 = csr_src[e + 6], i7 = csr_src[e + 7];
        for (int b = 0; b < nfull; ++b) {
            const u16* p0 = base + (size_t)i0 * stride + ch;
            const u16* p1 = base + (size_t)i1 * stride + ch;
            const u16* p2 = base + (size_t)i2 * stride + ch;
            const u16* p3 = base + (size_t)i3 * stride + ch;
            const u16* p4 = base + (size_t)i4 * stride + ch;
            const u16* p5 = base + (size_t)i5 * stride + ch;
            const u16* p6 = base + (size_t)i6 * stride + ch;
            const u16* p7 = base + (size_t)i7 * stride + ch;
            short8 a0 = *reinterpret_cast<const short8*>(p0), b0 = *reinterpret_cast<const short8*>(p0 + 8);
            short8 a1 = *reinterpret_cast<const short8*>(p1), b1 = *reinterpret_cast<const short8*>(p1 + 8);
            short8 a2 = *reinterpret_cast<const short8*>(p2), b2 = *reinterpret_cast<const short8*>(p2 + 8);
            short8 a3 = *reinterpret_cast<const short8*>(p3), b3 = *reinterpret_cast<const short8*>(p3 + 8);
            short8 a4 = *reinterpret_cast<const short8*>(p4), b4 = *reinterpret_cast<const short8*>(p4 + 8);
            short8 a5 = *reinterpret_cast<const short8*>(p5), b5 = *reinterpret_cast<const short8*>(p5 + 8);
            short8 a6 = *reinterpret_cast<const short8*>(p6), b6 = *reinterpret_cast<const short8*>(p6 + 8);
            short8 a7 = *reinterpret_cast<const short8*>(p7), b7 = *reinterpret_cast<const short8*>(p7 + 8);
            e += 8;
            // prefetch next batch's indices (clamped to beg: always valid, value unused
            // on last iteration). Issued above the barrier so they fly during the adds.
            int ep = (e + 8 <= end) ? e : beg;
            i0 = csr_src[ep];     i1 = csr_src[ep + 1]; i2 = csr_src[ep + 2]; i3 = csr_src[ep + 3];
            i4 = csr_src[ep + 4]; i5 = csr_src[ep + 5]; i6 = csr_src[ep + 6]; i7 = csr_src[ep + 7];
            __builtin_amdgcn_sched_barrier(0);
            add8v(acc, a0); add8v(acc + 8, b0);
            add8v(acc, a1); add8v(acc + 8, b1);
            add8v(acc, a2); add8v(acc + 8, b2);
            add8v(acc, a3); add8v(acc + 8, b3);
            add8v(acc, a4); add8v(acc + 8, b4);
            add8v(acc, a5); add8v(acc + 8, b5);
            add8v(acc, a6); add8v(acc + 8, b6);
            add8v(acc, a7); add8v(acc + 8, b7);
        }
    }
    for (; e + 4 <= end; e += 4) {
        const u16* p0 = base + (size_t)csr_src[e]     * stride + ch;
        const u16* p1 = base + (size_t)csr_src[e + 1] * stride + ch;
        const u16* p2 = base + (size_t)csr_src[e + 2] * stride + ch;
        const u16* p3 = base + (size_t)csr_src[e + 3] * stride + ch;
        short8 a0 = *reinterpret_cast<const short8*>(p0), b0 = *reinterpret_cast<const short8*>(p0 + 8);
        short8 a1 = *reinterpret_cast<const short8*>(p1), b1 = *reinterpret_cast<const short8*>(p1 + 8);
        short8 a2 = *reinterpret_cast<const short8*>(p2), b2 = *reinterpret_cast<const short8*>(p2 + 8);
        short8 a3 = *reinterpret_cast<const short8*>(p3), b3 = *reinterpret_cast<const short8*>(p3 + 8);
        __builtin_amdgcn_sched_barrier(0);
        add8v(acc, a0); add8v(acc + 8, b0);
        add8v(acc, a1); add8v(acc + 8, b1);
        add8v(acc, a2); add8v(acc + 8, b2);
        add8v(acc, a3); add8v(acc + 8, b3);
    }
    for (; e < end; ++e) {
        const u16* p = base + (size_t)csr_src[e] * stride + ch;
        short8 a = *reinterpret_cast<const short8*>(p), b = *reinterpret_cast<const short8*>(p + 8);
        add8v(acc, a); add8v(acc + 8, b);
    }
}

// ---------------- layer-1 pre-aggregation: Z[d] = bf16(dinv[d]*(Y[d]+sum Y[src])) ----------------
__global__ __launch_bounds__(256, 4) void agg_pre_kernel(
        const int* __restrict__ row_end, const int* __restrict__ cnt,
        const int* __restrict__ csr_src,
        const u16* __restrict__ Y, const float* __restrict__ dinv,
        u16* __restrict__ Z, int N) {
    int gid = blockIdx.x * blockDim.x + threadIdx.x;
    int node = gid >> 3;          // 8 threads/node
    int ch = (gid & 7) * 16;      // 16 cols each
    if (node >= N) return;
    float acc[16] = {};
    add16p(acc, Y + (size_t)node * 128 + ch);  // self-loop
    int end = row_end[node], beg = end - cnt[node];
    gather_sum16(acc, Y, csr_src, beg, end, 128, ch);
    float dv = dinv[node];
    short8 r0, r1;
#pragma unroll
    for (int w = 0; w < 8; ++w) {
        r0[w] = (short)f2bf(dv * acc[w]);
        r1[w] = (short)f2bf(dv * acc[8 + w]);
    }
    *reinterpret_cast<short8*>(Z + (size_t)node * 128 + ch) = r0;
    *reinterpret_cast<short8*>(Z + (size_t)node * 128 + ch + 8) = r1;
}

// ---------------- MFMA bf16 GEMM (generic BN/TPB; 64x64 wave tile avoids reg cliff) --------
// Out[N,F] from X[N,K] bf16 and Wt[F,K] bf16.
// EPI=0: Out = bf16(dinv[row] * acc)       EPI=1: Out = bf16(relu(acc + bias[col]))
// BM=128, BK=64. TPB=512 w/ BN=256: 8 waves in 2x4 grid, wave tile 64x64.
// LDS: slot c (16B) holds global chunk (r=c>>3, q=(c^r)&7); XOR swizzle keeps
// fragment ds_read_b128 conflict-free with linear wave-uniform gl2lds dest.
template <int BN, int TPB, int EPI>
__global__ __launch_bounds__(TPB) void gemm_mfma_kernel(
    const u16* __restrict__ X, const u16* __restrict__ Wt,
    const float* __restrict__ dinv, const float* __restrict__ bias,
    u16* __restrict__ Out, int N, int K, int F, int lgnx) {
    constexpr int BM = 128, BK = 64;
    constexpr int RA = (BM * 8) / TPB;
    constexpr int RB = (BN * 8) / TPB;
    constexpr int WAVES = TPB / 64;
    constexpr int WAVES_N = (BN >= 64) ? (BN / 64) : 1;   // 4 (BN=256) or 1 (BN=64)
    constexpr int WAVES_M = WAVES / WAVES_N;              // 2 or 4
    constexpr int WM = BM / WAVES_M;                      // 64 or 32
    constexpr int WN = BN / WAVES_N;                      // 64
    constexpr int NI = WM / 16;                           // 4 or 2
    constexpr int NJ = WN / 16;                           // 4
    __shared__ u16 As[BM * BK];   // 16 KB
    __shared__ u16 Bs[BN * BK];   // 32 KB (BN=256) or 8 KB (BN=64)

    const int t = threadIdx.x;
    const int wave = t >> 6;
    const int lane = t & 63;
    const int m16 = lane & 15;
    const int quad = lane >> 4;

    // XCD-aware decode
    const int id = blockIdx.x;
    const int wi = id & ((8 << lgnx) - 1);
    const int g  = id >> (3 + lgnx);
    const int rb = g * 8 + (wi & 7);
    const int cb = wi >> 3;
    const int row0 = rb * BM;
    const int col0 = cb * BN;
    if (row0 >= N) return;

    const int wm = (wave / WAVES_N) * WM;
    const int wn = (wave % WAVES_N) * WN;

    // ---- precompute staging pointers (global src advances by BK per iter) ----
    const u16* aSrc[RA];
    u16* aDst[RA];
#pragma unroll
    for (int rr = 0; rr < RA; ++rr) {
        int c = rr * TPB + t;
        int r = c >> 3;
        int q = (c ^ r) & 7;  // XOR swizzle
        int grow = row0 + r;
        if (grow >= N) grow = 0;  // clamped rows feed only epilogue-guarded outputs
        aSrc[rr] = X + (size_t)grow * K + q * 8;
        aDst[rr] = &As[(size_t)(rr * TPB + wave * 64) * 8];
    }
    const u16* bSrc[RB];
    u16* bDst[RB];
#pragma unroll
    for (int rr = 0; rr < RB; ++rr) {
        int c = rr * TPB + t;
        int r = c >> 3;
        int q = (c ^ r) & 7;
        bSrc[rr] = Wt + (size_t)(col0 + r) * K + q * 8;
        bDst[rr] = &Bs[(size_t)(rr * TPB + wave * 64) * 8];
    }

    // ---- fragment LDS byte offsets (u32, loop-invariant) ----
    u32 aOff[NI][2], bOff[NJ][2];
#pragma unroll
    for (int i = 0; i < NI; ++i)
#pragma unroll
        for (int h = 0; h < 2; ++h) {
            int row = wm + i * 16 + m16;
            int qg = h * 4 + quad;
            aOff[i][h] = (u32)(((row << 3) | ((qg ^ row) & 7)) * 16);
        }
#pragma unroll
    for (int j = 0; j < NJ; ++j)
#pragma unroll
        for (int h = 0; h < 2; ++h) {
            int row = wn + j * 16 + m16;
            int qg = h * 4 + quad;
            bOff[j][h] = (u32)(((row << 3) | ((qg ^ row) & 7)) * 16);
        }
    const char* AsB = reinterpret_cast<const char*>(As);
    const char* BsB = reinterpret_cast<const char*>(Bs);

    f32x4 acc[NI][NJ] = {};

    for (int k0 = 0; k0 < K; k0 += BK) {
#pragma unroll
        for (int rr = 0; rr < RA; ++rr) {
            gl2lds16(aSrc[rr], aDst[rr]);
            aSrc[rr] += BK;
        }
#pragma unroll
        for (int rr = 0; rr < RB; ++rr) {
            gl2lds16(bSrc[rr], bDst[rr]);
            bSrc[rr] += BK;
        }
        __syncthreads();  // drains vmcnt -> LDS valid

#pragma unroll
        for (int h = 0; h < 2; ++h) {  // two 16x16x32 k-slices per BK=64
            short8 af[NI], bf[NJ];
#pragma unroll
            for (int i = 0; i < NI; ++i)
                af[i] = *reinterpret_cast<const short8*>(AsB + aOff[i][h]);
#pragma unroll
            for (int j = 0; j < NJ; ++j)
                bf[j] = *reinterpret_cast<const short8*>(BsB + bOff[j][h]);
#pragma unroll
            for (int i = 0; i < NI; ++i)
#pragma unroll
                for (int j = 0; j < NJ; ++j)
                    acc[i][j] = __builtin_amdgcn_mfma_f32_16x16x32_bf16(af[i], bf[j], acc[i][j], 0, 0, 0);
        }
        __syncthreads();
    }

    // epilogue: C/D layout col=lane&15, row=quad*4+reg  [measured m89/m91]
#pragma unroll
    for (int i = 0; i < NI; ++i) {
#pragma unroll
        for (int r = 0; r < 4; ++r) {
            int grow = row0 + wm + i * 16 + quad * 4 + r;
            if (grow >= N) continue;
            float dv = (EPI == 0) ? dinv[grow] : 0.f;
#pragma unroll
            for (int j = 0; j < NJ; ++j) {
                int gcol = col0 + wn + j * 16 + m16;
                float v = acc[i][j][r];
                if (EPI == 0) v = dv * v;
                else          v = fmaxf(v + bias[gcol], 0.f);
                Out[(size_t)grow * F + gcol] = f2bf(v);
            }
        }
    }
}

// ---------------- post-aggregation: X_next = bf16(relu(dinv*(G[d]+sum G[src]) + b)) ----------------
// lgG = log2(F/16): 16 channels per thread
__global__ __launch_bounds__(256, 4) void agg_post_kernel(
        const int* __restrict__ row_end, const int* __restrict__ cnt,
        const int* __restrict__ csr_src,
        const u16* __restrict__ Gc, const float* __restrict__ dinv,
        const float* __restrict__ bias, u16* __restrict__ XO,
        int N, int F, int lgG) {
    int gid = blockIdx.x * blockDim.x + threadIdx.x;
    int node = gid >> lgG;
    int ch = (gid & ((1 << lgG) - 1)) * 16;
    if (node >= N) return;
    float acc[16] = {};
    add16p(acc, Gc + (size_t)node * F + ch);  // self-loop
    int end = row_end[node], beg = end - cnt[node];
    gather_sum16(acc, Gc, csr_src, beg, end, F, ch);
    float dv = dinv[node];
    short8 r0, r1;
#pragma unroll
    for (int w = 0; w < 8; ++w) {
        r0[w] = (short)f2bf(fmaxf(fmaf(dv, acc[w], bias[ch + w]), 0.f));
        r1[w] = (short)f2bf(fmaxf(fmaf(dv, acc[8 + w], bias[ch + 8 + w]), 0.f));
    }
    *reinterpret_cast<short8*>(XO + (size_t)node * F + ch) = r0;
    *reinterpret_cast<short8*>(XO + (size_t)node * F + ch + 8) = r1;
}

// ---------------- fused layer-4 aggregation + layer-5 dot ----------------
__global__ __launch_bounds__(256, 4) void agg_post_l5_kernel(
        const int* __restrict__ row_end, const int* __restrict__ cnt,
        const int* __restrict__ csr_src,
        const u16* __restrict__ Gc, const float* __restrict__ dinv,
        const float* __restrict__ b4, const float* __restrict__ W5,
        float* __restrict__ g5, int N) {
    int gid = blockIdx.x * blockDim.x + threadIdx.x;
    int node = gid >> 2;          // 4 threads/node
    int ch = (gid & 3) * 16;      // 16 cols each
    if (node >= N) return;
    float acc[16] = {};
    add16p(acc, Gc + (size_t)node * 64 + ch);  // self-loop
    int end = row_end[node], beg = end - cnt[node];
    gather_sum16(acc, Gc, csr_src, beg, end, 64, ch);
    float dv = dinv[node];
    float dot = 0.f;
#pragma unroll
    for (int w = 0; w < 16; ++w) {
        float v = fmaxf(fmaf(dv, acc[w], b4[ch + w]), 0.f);  // fp32 activation
        dot = fmaf(v, W5[ch + w], dot);
    }
#pragma unroll
    for (int off = 2; off > 0; off >>= 1) dot += __shfl_down(dot, off, 4);
    if ((gid & 3) == 0) g5[node] = dv * dot;
}

__global__ void agg5_kernel(const int* __restrict__ row_end, const int* __restrict__ cnt,
                            const int* __restrict__ csr_src,
                            const float* __restrict__ g5, const float* __restrict__ dinv,
                            const float* __restrict__ b5, float* __restrict__ out, int N) {
    int i = blockIdx.x * blockDim.x + threadIdx.x;
    if (i >= N) return;
    float acc = g5[i];
    int end = row_end[i], e = end - cnt[i];
    for (; e + 4 <= end; e += 4) {
        float a = g5[csr_src[e]];
        float b = g5[csr_src[e + 1]];
        float c = g5[csr_src[e + 2]];
        float d = g5[csr_src[e + 3]];
        acc += (a + b) + (c + d);
    }
    for (; e < end; ++e) acc += g5[csr_src[e]];
    out[i] = fmaxf(fmaf(dinv[i], acc, b5[0]), 0.f);
}

// ---------------- launch ----------------

static inline size_t align_up(size_t x) { return (x + 255) & ~(size_t)255; }
static inline int round_up8(int x) { return (x + 7) & ~7; }

extern "C" void kernel_launch(void* const* d_in, const int* in_sizes, int n_in,
                              void* d_out, int out_size, void* d_ws, size_t ws_size,
                              hipStream_t stream) {
    const float* x  = (const float*)d_in[0];
    const int*   ei = (const int*)d_in[1];
    const int E = in_sizes[1] / 2;
    const int N = in_sizes[0] / N_NODES_DIM0;
    const int* src = ei;
    const int* dst = ei + E;

    const float* W[5] = {(const float*)d_in[2], (const float*)d_in[4], (const float*)d_in[6],
                         (const float*)d_in[8], (const float*)d_in[10]};
    const float* B[5] = {(const float*)d_in[3], (const float*)d_in[5], (const float*)d_in[7],
                         (const float*)d_in[9], (const float*)d_in[11]};

    const int Ks[4] = {128, 1024, 512, 256};
    const int Fs[4] = {1024, 512, 256, 64};

    // workspace carve — peak ~209 MB
    char* w = (char*)d_ws;
    size_t off = 0;
    float* dinv    = (float*)(w + off); off += align_up((size_t)N * 4);
    float* g5      = (float*)(w + off); off += align_up((size_t)N * 4);
    int*   cnt     = (int*)(w + off);   off += align_up((size_t)(N + 1) * 4);  // cnt[N] = cursor
    int*   rstart  = (int*)(w + off);   off += align_up((size_t)N * 4);        // bump ptr -> row end
    int*   csr_src = (int*)(w + off);   off += align_up((size_t)E * 4);        // 1.6 MB
    u16* WtBase = (u16*)(w + off);
    u16* Wt[4];
    {
        size_t cum = 0;
        for (int l = 0; l < 4; ++l) {
            Wt[l] = WtBase + cum;
            cum += (size_t)Ks[l] * Fs[l];
        }
        off += align_up(cum * 2);
    }
    char* REG = w + off;               off += align_up((size_t)N * 512 * 2);    // 51.2 MB
    u16* Y  = (u16*)REG;
    u16* Z  = (u16*)(REG + align_up((size_t)N * 128 * 2));
    u16* Gc = (u16*)REG;
    u16* XA = (u16*)(w + off);         off += align_up((size_t)N * 1024 * 2);   // 102.4 MB
    u16* XB = (u16*)(w + off);         off += align_up((size_t)N * 512 * 2);    // 51.2 MB
    (void)ws_size;

    // ---- CSR build (scan-free) ----
    hipMemsetAsync(cnt, 0, (size_t)(N + 1) * 4, stream);
    hist_kernel<<<(E + 255) / 256, 256, 0, stream>>>(dst, cnt, E);
    alloc_kernel<<<(N + 255) / 256, 256, 0, stream>>>(cnt, rstart, dinv, &cnt[N], N);
    fill_kernel<<<(E + 255) / 256, 256, 0, stream>>>(src, dst, rstart, csr_src, E);

    // ---- weights transpose-cast + input scale-cast, single merged launch ----
    {
        int scale_blocks = (N * 32 + 255) / 256;
        prep_kernel<<<784 + scale_blocks, 256, 0, stream>>>(
            W[0], W[1], W[2], W[3], WtBase, x, dinv, Y, N);
    }

    const int ny = (N + 127) / 128;
    const int ny8 = round_up8(ny);

    // ---- layer 1: aggregate-first (K=128 < F=1024) ----
    agg_pre_kernel<<<(N * 8 + 255) / 256, 256, 0, stream>>>(rstart, cnt, csr_src, Y, dinv, Z, N);
    {
        // F=1024, BN=256 -> nx=4, lgnx=2
        gemm_mfma_kernel<256, 512, 1><<<ny8 * 4, 512, 0, stream>>>(Z, Wt[0], dinv, B[0], XA,
                                                                   N, 128, 1024, 2);
    }

    // ---- layers 2..4: GEMM (dinv epilogue) -> aggregate; layer-4 agg fuses layer-5 dot ----
    u16* Xin[3]  = {XA, XB, XA};
    u16* Xout[3] = {XB, XA, nullptr};
    for (int l = 1; l < 4; ++l) {
        const int K = Ks[l], F = Fs[l];
        if (F >= 256) {
            int nx = F / 256;                  // 2 (F=512) or 1 (F=256)
            int lgnx = (nx == 2) ? 1 : 0;
            gemm_mfma_kernel<256, 512, 0><<<ny8 * nx, 512, 0, stream>>>(
                Xin[l - 1], Wt[l], dinv, B[l], Gc, N, K, F, lgnx);
        } else {
            // F=64, BN=64 -> nx=1, lgnx=0
            gemm_mfma_kernel<64, 256, 0><<<ny8, 256, 0, stream>>>(
                Xin[l - 1], Wt[l], dinv, B[l], Gc, N, K, F, 0);
        }
        if (l < 3) {
            int lgG = (F == 512) ? 5 : 4;  // F/16 threads per node
            long long tot = (long long)N << lgG;
            agg_post_kernel<<<(unsigned)((tot + 255) / 256), 256, 0, stream>>>(
                rstart, cnt, csr_src, Gc, dinv, B[l], Xout[l - 1], N, F, lgG);
        } else {
            long long tot = (long long)N << 2;
            agg_post_l5_kernel<<<(unsigned)((tot + 255) / 256), 256, 0, stream>>>(
                rstart, cnt, csr_src, Gc, dinv, B[3], W[4], g5, N);
        }
    }

    // ---- layer 5 aggregation: out = relu(dinv*(g5[d]+sum g5[src]) + b5) ----
    agg5_kernel<<<(N + 255) / 256, 256, 0, stream>>>(rstart, cnt, csr_src, g5, dinv, B[4],
                                                     (float*)d_out, N);
}